// Round 4
// baseline (125.307 us; speedup 1.0000x reference)
//
#include <hip/hip_runtime.h>
#include <hip/hip_bf16.h>

#define BATCH 16384
#define DIM   512
#define UNITS 1024
// GAMMA = 0.5 folded into epilogue: out = exp(cross - 0.5*xsq - 0.5*musq)

typedef float v16f __attribute__((ext_vector_type(16)));

__device__ __forceinline__ void async_copy16(const void* g, void* l) {
    __builtin_amdgcn_global_load_lds(
        (const __attribute__((address_space(1))) void*)g,
        (__attribute__((address_space(3))) void*)l,
        16 /*bytes*/, 0 /*offset*/, 0 /*aux*/);
}

// Fused prep: blocks [0,4096): inputs fp32 -> A8 fp8 + xsq (one wave/row).
//             blocks [4096,4112): mu -> B8 fp8 (transposed) + musq.
// xsq/musq computed on ORIGINAL fp32 values (pre-quantization).
__global__ __launch_bounds__(256)
void prep_kernel(const float* __restrict__ in, const float* __restrict__ mu,
                 unsigned char* __restrict__ A8, unsigned char* __restrict__ B8,
                 float* __restrict__ xsq, float* __restrict__ musq) {
    __shared__ float lds[64][65];
    __shared__ float red[64][4];
    const int t = threadIdx.x;
    if (blockIdx.x < BATCH / 4) {
        const int lane = t & 63;
        const int row  = blockIdx.x * 4 + (t >> 6);
        const float4* src = (const float4*)(in + (size_t)row * DIM);
        float4 a = src[lane * 2];
        float4 b = src[lane * 2 + 1];
        float s = a.x * a.x + a.y * a.y + a.z * a.z + a.w * a.w
                + b.x * b.x + b.y * b.y + b.z * b.z + b.w * b.w;
        int lo = __builtin_amdgcn_cvt_pk_fp8_f32(a.x, a.y, 0, false);
        lo     = __builtin_amdgcn_cvt_pk_fp8_f32(a.z, a.w, lo, true);
        int hi = __builtin_amdgcn_cvt_pk_fp8_f32(b.x, b.y, 0, false);
        hi     = __builtin_amdgcn_cvt_pk_fp8_f32(b.z, b.w, hi, true);
        *(int2*)(A8 + (size_t)row * DIM + lane * 8) = make_int2(lo, hi);
        for (int off = 32; off; off >>= 1) s += __shfl_down(s, off, 64);
        if (lane == 0) xsq[row] = s;
    } else {
        const int n0 = (blockIdx.x - BATCH / 4) * 64;
        const int c  = t & 63, r4 = t >> 6;     // load phase
        const int nl = t >> 2, kp = t & 3;      // write phase
        float s = 0.f;
        for (int kc = 0; kc < DIM; kc += 64) {
            __syncthreads();
#pragma unroll
            for (int i = 0; i < 16; i++)
                lds[r4 + i * 4][c] = mu[(size_t)(kc + r4 + i * 4) * UNITS + n0 + c];
            __syncthreads();
            int wr[4];
#pragma unroll
            for (int q = 0; q < 4; q++) {
                float f0 = lds[kp * 16 + q * 4 + 0][nl];
                float f1 = lds[kp * 16 + q * 4 + 1][nl];
                float f2 = lds[kp * 16 + q * 4 + 2][nl];
                float f3 = lds[kp * 16 + q * 4 + 3][nl];
                s += f0 * f0 + f1 * f1 + f2 * f2 + f3 * f3;
                int v = __builtin_amdgcn_cvt_pk_fp8_f32(f0, f1, 0, false);
                wr[q]  = __builtin_amdgcn_cvt_pk_fp8_f32(f2, f3, v, true);
            }
            *(int4*)(B8 + (size_t)(n0 + nl) * DIM + kc + kp * 16) =
                make_int4(wr[0], wr[1], wr[2], wr[3]);
        }
        red[nl][kp] = s;
        __syncthreads();
        if (t < 64) musq[n0 + t] = red[t][0] + red[t][1] + red[t][2] + red[t][3];
    }
}

// 128x128-tile fp8 GEMM, BK=128 (4 K-iters), 4 waves/block, 4 blocks/CU.
// XCD-swizzled grid: XCD x owns a contiguous 2048-row A slice (1 MB fp8,
// L2-resident) x all 8 N-tiles -> A re-reads are L2 hits, not L3.
// LDS: 128 rows x 128 fp8, 128-B row stride, 16B-slot XOR swizzle
// (stored slot = logical ^ (row&7)); swizzle applied on the WRITE side by
// permuting each lane's global chunk (global_load_lds is lane-linear), on
// the READ side in the frag address -> b64 reads at the 4-cyc structural
// floor (4 lanes/bank-pair, all 32 banks busy).
__global__ __launch_bounds__(256, 4)
void rbf_gemm_kernel(const unsigned char* __restrict__ A8,
                     const unsigned char* __restrict__ B8,
                     const float* __restrict__ xsq,
                     const float* __restrict__ musq,
                     float* __restrict__ out) {
    __shared__ __attribute__((aligned(16))) unsigned char As[128 * 128];
    __shared__ __attribute__((aligned(16))) unsigned char Bs[128 * 128];

    const int t   = threadIdx.x;
    const int l   = t & 63;
    const int wv  = t >> 6;
    const int ln  = l & 31;
    const int h   = l >> 5;           // k-half of fragment
    const int wmr = (wv >> 1) * 64;   // wave sub-tile origin
    const int wnr = (wv & 1) * 64;

    const int g   = blockIdx.x;       // 1024 blocks
    const int mt  = (g & 7) * 16 + (g >> 6);        // XCD-contiguous M
    const int nt  = (g >> 3) & 7;
    const int m0  = mt * 128;
    const int n0  = nt * 128;

    v16f acc[2][2];
#pragma unroll
    for (int i = 0; i < 2; i++)
#pragma unroll
        for (int j = 0; j < 2; j++) acc[i][j] = (v16f)0.f;

    // Staging: issue i covers rows [i*32, i*32+32); thread t -> row i*32+(t>>3),
    // stored slot t&7 which holds logical slot (t&7)^(row&7).
    const int srow = t >> 3;
    const int gsl  = (t & 7) ^ (srow & 7);
    const unsigned char* ga = A8 + (size_t)(m0 + srow) * DIM + gsl * 16;
    const unsigned char* gb = B8 + (size_t)(n0 + srow) * DIM + gsl * 16;
    const int sw = ln & 7;            // read-side swizzle key

    for (int kt = 0; kt < 4; kt++) {
        const int kc = kt * 128;
        if (kt) __syncthreads();      // all waves done reading LDS
#pragma unroll
        for (int i = 0; i < 4; i++) {
            async_copy16(ga + (size_t)i * 32 * DIM + kc, As + i * 4096 + t * 16);
            async_copy16(gb + (size_t)i * 32 * DIM + kc, Bs + i * 4096 + t * 16);
        }
        __syncthreads();

#pragma unroll
        for (int w = 0; w < 8; w++) { // k-window of 16 within BK=128
            const int so = ((w ^ sw) * 16) + 8 * h;
            long a0 = *(const long*)(As + (wmr + ln) * 128 + so);
            long a1 = *(const long*)(As + (wmr + 32 + ln) * 128 + so);
            long b0 = *(const long*)(Bs + (wnr + ln) * 128 + so);
            long b1 = *(const long*)(Bs + (wnr + 32 + ln) * 128 + so);
            acc[0][0] = __builtin_amdgcn_mfma_f32_32x32x16_fp8_fp8(a0, b0, acc[0][0], 0, 0, 0);
            acc[0][1] = __builtin_amdgcn_mfma_f32_32x32x16_fp8_fp8(a0, b1, acc[0][1], 0, 0, 0);
            acc[1][0] = __builtin_amdgcn_mfma_f32_32x32x16_fp8_fp8(a1, b0, acc[1][0], 0, 0, 0);
            acc[1][1] = __builtin_amdgcn_mfma_f32_32x32x16_fp8_fp8(a1, b1, acc[1][1], 0, 0, 0);
        }
    }

    // Epilogue. C/D layout (m74/m101, dtype-indep): col = l&31,
    // row = (reg&3) + 8*(reg>>2) + 4*(l>>5).
    const float xv = -0.5f * xsq[m0 + wmr + l];   // lane l holds row wmr+l
#pragma unroll
    for (int ti = 0; ti < 2; ti++) {
#pragma unroll
        for (int tj = 0; tj < 2; tj++) {
            const int c0 = n0 + wnr + tj * 32 + ln;
            const float mb = -0.5f * musq[c0];
#pragma unroll
            for (int r = 0; r < 16; r++) {
                const int rl = (r & 3) + 8 * (r >> 2) + 4 * h;  // 0..31
                const float xb = __shfl(xv, ti * 32 + rl, 64);
                float v = __expf(acc[ti][tj][r] + xb + mb);
                __builtin_nontemporal_store(
                    v, out + (size_t)(m0 + wmr + ti * 32 + rl) * UNITS + c0);
            }
        }
    }
}

extern "C" void kernel_launch(void* const* d_in, const int* in_sizes, int n_in,
                              void* d_out, int out_size, void* d_ws, size_t ws_size,
                              hipStream_t stream) {
    const float* inputs = (const float*)d_in[0];   // [16384, 512] fp32
    const float* mu     = (const float*)d_in[1];   // [512, 1024] fp32
    float* out = (float*)d_out;                    // [16384, 1024] fp32

    char* ws = (char*)d_ws;
    unsigned char* A8 = (unsigned char*)ws;                            // 8 MiB
    unsigned char* B8 = (unsigned char*)(ws + (size_t)BATCH * DIM);    // 512 KiB
    float* xsq  = (float*)(ws + (size_t)BATCH * DIM + (size_t)UNITS * DIM);
    float* musq = xsq + BATCH;

    prep_kernel<<<BATCH / 4 + UNITS / 64, 256, 0, stream>>>(
        inputs, mu, A8, B8, xsq, musq);
    rbf_gemm_kernel<<<(BATCH / 128) * (UNITS / 128), 256, 0, stream>>>(
        A8, B8, xsq, musq, out);
}